// Round 7
// baseline (196.936 us; speedup 1.0000x reference)
//
#include <hip/hip_runtime.h>
#include <math.h>

// Problem constants
#define B_SZ 2
#define SEQ 2048
#define DMODEL 1024
#define NH 16
#define DK 64
#define NQKV 3072
#define M_ROWS 4096

#define NEG_BIG (-3.0e38f)
#define SCL 0.18033688011112042f   // 0.125 * log2(e)

typedef short short8 __attribute__((ext_vector_type(8)));
typedef float v4f __attribute__((ext_vector_type(4)));
typedef unsigned short ushort_t;

__device__ inline ushort_t f2bf(float f) {
    unsigned u = __float_as_uint(f);
    u += 0x7fffu + ((u >> 16) & 1u);   // RNE
    return (ushort_t)(u >> 16);
}

// packed f32x2 -> bf16x2 (RNE), single VALU op
__device__ __forceinline__ unsigned cvt_pk_bf16(float lo, float hi) {
    unsigned r;
    asm("v_cvt_pk_bf16_f32 %0, %1, %2" : "=v"(r) : "v"(lo), "v"(hi));
    return r;
}
__device__ __forceinline__ void permlane32_swap(unsigned &a, unsigned &b) {
    asm("v_permlane32_swap_b32 %0, %1" : "+v"(a), "+v"(b));
}
__device__ __forceinline__ void permlane16_swap(unsigned &a, unsigned &b) {
    asm("v_permlane16_swap_b32 %0, %1" : "+v"(a), "+v"(b));
}

// async global(16B/lane) -> LDS (wave-uniform base + lane*16)
__device__ __forceinline__ void gl_lds16(const ushort_t* g, ushort_t* l) {
    __builtin_amdgcn_global_load_lds(
        (const __attribute__((address_space(1))) unsigned int*)g,
        (__attribute__((address_space(3))) unsigned int*)l, 16, 0, 0);
}

// attn K/V LDS addressing: [64 rows][64 cols] bf16 (128B rows, UNPADDED),
// 16B-slot XOR swizzle: slot8 ^= (row&7). Conflict-free on both the
// staging-write and fragment-read paths (verified R6: conflicts ~0).
__device__ __forceinline__ int kvaddr(int row, int col8) {
    return row * 64 + ((col8 ^ (row & 7)) << 3);
}

// ---------------------------------------------------------------------------
// Kernel 0: fused prep — fp32->bf16 converts (x, Wa, Wo) + RoPE tables.
// RoPE cos/sin COMPUTED from theta/position (33.5 MB rope tensor never read;
// verified R4-R6: absmax unchanged).
// ---------------------------------------------------------------------------
__global__ __launch_bounds__(256) void prep_kernel(
    const float* __restrict__ x, const float* __restrict__ Wa,
    const float* __restrict__ Wo, const float* __restrict__ rope,
    ushort_t* __restrict__ xb, ushort_t* __restrict__ Wab, ushort_t* __restrict__ Wob,
    float* __restrict__ cosT, float* __restrict__ sinT)
{
    (void)rope;
    const int bid = blockIdx.x;
    if (bid < 8192) {
        const float* src; ushort_t* dst; int i;
        if (bid < 4096)      { src = x;  dst = xb;  i = bid * 256 + threadIdx.x; }
        else if (bid < 7168) { src = Wa; dst = Wab; i = (bid - 4096) * 256 + threadIdx.x; }
        else                 { src = Wo; dst = Wob; i = (bid - 7168) * 256 + threadIdx.x; }
        float4 v = reinterpret_cast<const float4*>(src)[i];
        ushort4 r;
        r.x = f2bf(v.x); r.y = f2bf(v.y); r.z = f2bf(v.z); r.w = f2bf(v.w);
        reinterpret_cast<ushort4*>(dst)[i] = r;
    } else {
        const int i = (bid - 8192) * 256 + threadIdx.x;   // [0, 2048*64)
        const int p = i >> 6, d = i & 63;
        // inv_freq = theta^(-2*(d/2)/64) = exp2(-log2(1e4)/32 * (d>>1))
        const float inv = exp2f(-0.4152410118609203f * (float)(d >> 1));
        const float ang = (float)p * inv;
        float sv, cv;
        sincosf(ang, &sv, &cv);
        cosT[i] = cv;
        sinT[i] = (d & 1) ? sv : -sv;
    }
}

// ---------------------------------------------------------------------------
// Kernel 1: QKV projection + RoPE (R2-verified: 128x128 tile, BK=64,
// XOR-swizzled gl_lds staging, double-buffered, counted vmcnt(8) across raw
// s_barrier, setprio around MFMA, bijective XCD-chunked swizzle).
// Q pre-scaled by SCL = 0.125*log2(e).
// ---------------------------------------------------------------------------
#define ES_STRIDE 136

#define QKV_STAGE(bofs, k0s)                                                   \
    _Pragma("unroll")                                                          \
    for (int j = 0; j < 4; ++j)                                                \
        gl_lds16(&Wab[(size_t)(e0 + srow[j]) * DMODEL + (k0s) + skc[j]],       \
                 &qkv_smem[(bofs) + (tid + 256 * j) * 8]);                     \
    _Pragma("unroll")                                                          \
    for (int j = 4; j < 8; ++j)                                                \
        gl_lds16(&xb[(size_t)(m0 + srow[j]) * DMODEL + (k0s) + skc[j]],        \
                 &qkv_smem[(bofs) + (tid + 256 * j) * 8]);

__global__ __launch_bounds__(256) void qkv_mfma_kernel(
    const ushort_t* __restrict__ xb,   // [4096,1024] bf16
    const ushort_t* __restrict__ Wab,  // [3072,1024] bf16
    const float* __restrict__ cosT, const float* __restrict__ sinT,
    const int* __restrict__ tpos,
    ushort_t* __restrict__ Qb, ushort_t* __restrict__ Kb, ushort_t* __restrict__ Vtb)
{
    __shared__ ushort_t qkv_smem[32768];   // 64 KB: 2 staging buffers
    ushort_t* Es = qkv_smem;               // [128][ES_STRIDE] epilogue alias

    const int tid = threadIdx.x;
    const int w = tid >> 6, lane = tid & 63;
    const int lm = lane & 15, g = lane >> 4;
    const int wm = (w >> 1) * 64, wn = (w & 1) * 64;   // wm: e-dim, wn: m-dim

    // T1: bijective XCD-chunked swizzle (768 = 8 * 96)
    const int lid = blockIdx.y * 24 + blockIdx.x;
    const int swz = (lid & 7) * 96 + (lid >> 3);
    const int e0 = (swz % 24) * 128, m0 = (swz / 24) * 128;

    int srow[8], skc[8];
#pragma unroll
    for (int j = 0; j < 8; ++j) {
        const int c = tid + 256 * j;          // phys chunk 0..2047
        const int cm = c & 1023;
        const int row = cm >> 3, pp = cm & 7;
        srow[j] = row;
        skc[j] = (pp ^ (row & 7)) * 8;        // logical k offset (ushorts)
    }

    v4f acc[4][4] = {};

    QKV_STAGE(0, 0);                          // prologue: tile 0 -> buf0

    for (int t = 0; t < 16; ++t) {
        const int bofs = (t & 1) << 14;       // 0 / 16384 ushorts
        if (t < 15) {
            const int nofs = ((t + 1) & 1) << 14;
            QKV_STAGE(nofs, (t + 1) * 64);    // prefetch next tile (stays in flight)
            __builtin_amdgcn_sched_barrier(0);
            asm volatile("s_waitcnt vmcnt(8)" ::: "memory");   // wait cur's 8 only
        } else {
            __builtin_amdgcn_sched_barrier(0);
            asm volatile("s_waitcnt vmcnt(0)" ::: "memory");
        }
        __builtin_amdgcn_s_barrier();         // cur tile visible to all waves
        __builtin_amdgcn_sched_barrier(0);

        __builtin_amdgcn_s_setprio(1);
#pragma unroll
        for (int kb = 0; kb < 2; ++kb) {
            short8 af[4], bfr[4];
#pragma unroll
            for (int mf = 0; mf < 4; ++mf) {
                const int r = wm + mf * 16 + lm;
                af[mf] = *reinterpret_cast<const short8*>(
                    &qkv_smem[bofs + (r * 8 + ((kb * 4 + g) ^ (r & 7))) * 8]);
            }
#pragma unroll
            for (int nf = 0; nf < 4; ++nf) {
                const int r = wn + nf * 16 + lm;
                bfr[nf] = *reinterpret_cast<const short8*>(
                    &qkv_smem[bofs + 8192 + (r * 8 + ((kb * 4 + g) ^ (r & 7))) * 8]);
            }
#pragma unroll
            for (int mf = 0; mf < 4; ++mf)
#pragma unroll
                for (int nf = 0; nf < 4; ++nf)
                    acc[mf][nf] = __builtin_amdgcn_mfma_f32_16x16x32_bf16(af[mf], bfr[nf], acc[mf][nf], 0, 0, 0);
        }
        __builtin_amdgcn_s_setprio(0);

        __builtin_amdgcn_sched_barrier(0);
        __builtin_amdgcn_s_barrier();         // reads of buf[cur] done before overwrite
        __builtin_amdgcn_sched_barrier(0);
    }

    __syncthreads();   // full fence; Es aliases staging

    const int which = e0 >> 10;            // 0=Q,1=K,2=V (block-uniform)
    const int h0 = (e0 & 1023) >> 6;
    const int bb = m0 >> 11, s0 = m0 & 2047;

    if (which < 2) {
        ushort_t* buf = (which == 0) ? Qb : Kb;
        const float qs = (which == 0) ? SCL : 1.0f;   // fold softmax scale into Q
#pragma unroll
        for (int mf = 0; mf < 4; ++mf) {
            const int ebase = wm + mf * 16 + g * 4;
            const int d0 = (e0 + ebase) & 63;
#pragma unroll
            for (int nf = 0; nf < 4; ++nf) {
                const int sloc = wn + nf * 16 + lm;
                float v[4] = {acc[mf][nf][0], acc[mf][nf][1], acc[mf][nf][2], acc[mf][nf][3]};
                const int p = tpos[s0 + sloc];
                const float4 c4 = *reinterpret_cast<const float4*>(&cosT[p * 64 + d0]);
                const float4 s4 = *reinterpret_cast<const float4*>(&sinT[p * 64 + d0]);
                const float r0 = (c4.x * v[0] + s4.x * v[1]) * qs;
                const float r1 = (c4.y * v[1] + s4.y * v[0]) * qs;
                const float r2 = (c4.z * v[2] + s4.z * v[3]) * qs;
                const float r3 = (c4.w * v[3] + s4.w * v[2]) * qs;
                uint2 pp;
                pp.x = (unsigned)f2bf(r0) | ((unsigned)f2bf(r1) << 16);
                pp.y = (unsigned)f2bf(r2) | ((unsigned)f2bf(r3) << 16);
                *reinterpret_cast<uint2*>(&Es[sloc * ES_STRIDE + ebase]) = pp;
            }
        }
        __syncthreads();
#pragma unroll
        for (int hh = 0; hh < 2; ++hh) {
            ushort_t* dst = buf + (((size_t)bb * NH + h0 + hh) * SEQ + s0) * DK;
#pragma unroll
            for (int t = 0; t < 4; ++t) {
                const int o = (t * 256 + tid) * 8;
                const int sloc = o >> 6, d = o & 63;
                const short8 vv = *reinterpret_cast<const short8*>(&Es[sloc * ES_STRIDE + hh * 64 + d]);
                *reinterpret_cast<short8*>(&dst[o]) = vv;
            }
        }
    } else {
        // V: write Es TRANSPOSED [e_loc][s_loc], store [d][s] slabs to Vtb.
#pragma unroll
        for (int mf = 0; mf < 4; ++mf) {
            const int ebase = wm + mf * 16 + g * 4;
#pragma unroll
            for (int nf = 0; nf < 4; ++nf) {
                const int sloc = wn + nf * 16 + lm;
                Es[(ebase + 0) * ES_STRIDE + sloc] = f2bf(acc[mf][nf][0]);
                Es[(ebase + 1) * ES_STRIDE + sloc] = f2bf(acc[mf][nf][1]);
                Es[(ebase + 2) * ES_STRIDE + sloc] = f2bf(acc[mf][nf][2]);
                Es[(ebase + 3) * ES_STRIDE + sloc] = f2bf(acc[mf][nf][3]);
            }
        }
        __syncthreads();
#pragma unroll
        for (int t = 0; t < 8; ++t) {
            const int c = t * 256 + tid;
            const int hh = c >> 10, cm = c & 1023;
            const int d = cm >> 4, s8c = (cm & 15) * 8;
            const short8 vv = *reinterpret_cast<const short8*>(&Es[(hh * 64 + d) * ES_STRIDE + s8c]);
            ushort_t* dst = Vtb + ((size_t)bb * NH + h0 + hh) * SEQ * DK + (size_t)d * SEQ + s0 + s8c;
            *reinterpret_cast<short8*>(dst) = vv;
        }
    }
}

// ---------------------------------------------------------------------------
// Kernel 2: flash attention — R6-verified structure (merged q-tile pairs,
// register prefetch -> dbuf LDS -> single barrier/iter, XOR-swizzled
// conflict-free K/V tiles, VALU-diet softmax). NEW (R7): XCD-aware work
// remap — each XCD owns 4 (b,h) pairs x all 16 u-blocks, so its K/V working
// set is 2 MB (L2-resident) instead of ~16 MB (thrash). Pure index remap;
// relies on bid%8 XCD round-robin for locality only (correctness-safe).
// ---------------------------------------------------------------------------
#define ATTN_STEP(QF0, QF1, QROW, LACC, OACC, DIAG, C0)                           \
    {                                                                             \
        v4f sacc[4] = {};                                                         \
        _Pragma("unroll")                                                         \
        for (int nf = 0; nf < 4; ++nf) {                                          \
            sacc[nf] = __builtin_amdgcn_mfma_f32_16x16x32_bf16(kf[nf][0], QF0, sacc[nf], 0, 0, 0); \
            sacc[nf] = __builtin_amdgcn_mfma_f32_16x16x32_bf16(kf[nf][1], QF1, sacc[nf], 0, 0, 0); \
        }                                                                         \
        if (DIAG) {                                                               \
            _Pragma("unroll")                                                     \
            for (int nf = 0; nf < 4; ++nf)                                        \
                _Pragma("unroll")                                                 \
                for (int reg = 0; reg < 4; ++reg) {                               \
                    const int kv = (C0) + nf * 16 + g * 4 + reg;                  \
                    if (kv > (QROW)) sacc[nf][reg] = NEG_BIG;                     \
                }                                                                 \
        }                                                                         \
        unsigned pk0[8];                                                          \
        _Pragma("unroll")                                                         \
        for (int nf = 0; nf < 4; ++nf) {                                          \
            pk0[nf * 2]     = cvt_pk_bf16(exp2f(sacc[nf][0]), exp2f(sacc[nf][1])); \
            pk0[nf * 2 + 1] = cvt_pk_bf16(exp2f(sacc[nf][2]), exp2f(sacc[nf][3])); \
        }                                                                         \
        _Pragma("unroll")                                                         \
        for (int kc = 0; kc < 2; ++kc) {                                          \
            unsigned x0 = pk0[kc * 4 + 0], y0 = pk0[kc * 4 + 2];                  \
            unsigned x1 = pk0[kc * 4 + 1], y1 = pk0[kc * 4 + 3];                  \
            permlane32_swap(x0, y0); permlane16_swap(x0, y0);                     \
            permlane32_swap(x1, y1); permlane16_swap(x1, y1);                     \
            union { unsigned u[4]; short8 s; } pu;                                \
            pu.u[0] = x0; pu.u[1] = x1; pu.u[2] = y0; pu.u[3] = y1;               \
            const short8 pf = pu.s;                                               \
            LACC = __builtin_amdgcn_mfma_f32_16x16x32_bf16(ones8, pf, LACC, 0, 0, 0); \
            _Pragma("unroll")                                                     \
            for (int df = 0; df < 4; ++df)                                        \
                OACC[df] = __builtin_amdgcn_mfma_f32_16x16x32_bf16(vf[df][kc], pf, OACC[df], 0, 0, 0); \
        }                                                                         \
    }

__global__ __launch_bounds__(256, 2) void attn_mfma_kernel(
    const ushort_t* __restrict__ Qb, const ushort_t* __restrict__ Kb,
    const ushort_t* __restrict__ Vtb, ushort_t* __restrict__ attb)
{
    __shared__ ushort_t Ks[2][4096];   // [buf] 64x64 bf16, XOR-swizzled slots
    __shared__ ushort_t Vs[2][4096];   // [buf] 64(d) x 64(kv), same swizzle

    const int tid = threadIdx.x;
    const int w = tid >> 6, lane = tid & 63;
    const int lm = lane & 15, g = lane >> 4, lk8 = g * 8;

    // XCD-aware remap: xcd = L&7 (HW round-robin), slot = L>>3.
    // Each XCD: 4 (b,h) pairs x 16 u-blocks -> K/V working set 2 MB < 4 MB L2.
    const int L = blockIdx.x;
    const int slot = L >> 3;
    const int u = slot & 15;                      // 0..15
    const int bh = (L & 7) * 4 + (slot >> 4);     // 0..31
    const int h = bh & 15, b = bh >> 4;

    const size_t ho = ((size_t)b * NH + h) * SEQ * DK;
    const ushort_t* Qh = Qb + ho;
    const ushort_t* Kh = Kb + ho;
    const ushort_t* Vth = Vtb + ho;               // [DK][SEQ]

    // staging decode: row = tid>>3, 16B chunk c8 = tid&7 (global col c8*8)
    const int rr0 = tid >> 3, c80 = tid & 7;
    const int rr1 = rr0 + 32, c81 = c80;
    const int sw0 = kvaddr(rr0, c80);             // swizzled LDS ushort offset
    const int sw1 = kvaddr(rr1, c81);
    const int gc0 = c80 * 8, gc1 = c81 * 8;       // global col (ushorts)

    const int it1 = u, it2 = 31 - u;              // it1 <= it2 (u < 16)
    const int qrowA = it1 * 64 + w * 16 + lm;
    const int qrowB = it2 * 64 + w * 16 + lm;

    const short8 qa0 = *reinterpret_cast<const short8*>(&Qh[(size_t)qrowA * DK + lk8]);
    const short8 qa1 = *reinterpret_cast<const short8*>(&Qh[(size_t)qrowA * DK + 32 + lk8]);
    const short8 qb0 = *reinterpret_cast<const short8*>(&Qh[(size_t)qrowB * DK + lk8]);
    const short8 qb1 = *reinterpret_cast<const short8*>(&Qh[(size_t)qrowB * DK + 32 + lk8]);

    const short8 ones8 = {16256, 16256, 16256, 16256, 16256, 16256, 16256, 16256}; // bf16 1.0

    v4f laccA = {}, laccB = {};
    v4f OA[4] = {}, OB[4] = {};

    // preload jt=0
    short8 kreg[2], vreg[2];
    kreg[0] = *reinterpret_cast<const short8*>(&Kh[(size_t)rr0 * DK + gc0]);
    kreg[1] = *reinterpret_cast<const short8*>(&Kh[(size_t)rr1 * DK + gc1]);
    vreg[0] = *reinterpret_cast<const short8*>(&Vth[(size_t)rr0 * SEQ + gc0]);
    vreg[1] = *reinterpret_cast<const short8*>(&Vth[(size_t)rr1 * SEQ + gc1]);

    for (int jt = 0; jt <= it2; ++jt) {
        const int c0 = jt * 64;
        const int bufi = jt & 1;
        ushort_t* Ksb = Ks[bufi];
        ushort_t* Vsb = Vs[bufi];

        *reinterpret_cast<short8*>(&Ksb[sw0]) = kreg[0];
        *reinterpret_cast<short8*>(&Ksb[sw1]) = kreg[1];
        *reinterpret_cast<short8*>(&Vsb[sw0]) = vreg[0];
        *reinterpret_cast<short8*>(&Vsb[sw1]) = vreg[1];

        if (jt < it2) {    // prefetch next tile; latency hides behind compute
            const int c0n = c0 + 64;
            kreg[0] = *reinterpret_cast<const short8*>(&Kh[(size_t)(c0n + rr0) * DK + gc0]);
            kreg[1] = *reinterpret_cast<const short8*>(&Kh[(size_t)(c0n + rr1) * DK + gc1]);
            vreg[0] = *reinterpret_cast<const short8*>(&Vth[(size_t)rr0 * SEQ + c0n + gc0]);
            vreg[1] = *reinterpret_cast<const short8*>(&Vth[(size_t)rr1 * SEQ + c0n + gc1]);
        }

        __syncthreads();   // single barrier per iter; dbuf handles WAR

        // shared K/V fragment loads (both q-tiles consume the same tile)
        short8 kf[4][2], vf[4][2];
#pragma unroll
        for (int nf = 0; nf < 4; ++nf) {
            const int r = nf * 16 + lm;
            kf[nf][0] = *reinterpret_cast<const short8*>(&Ksb[kvaddr(r, g)]);
            kf[nf][1] = *reinterpret_cast<const short8*>(&Ksb[kvaddr(r, 4 + g)]);
        }
#pragma unroll
        for (int df = 0; df < 4; ++df) {
            const int r = df * 16 + lm;
            vf[df][0] = *reinterpret_cast<const short8*>(&Vsb[kvaddr(r, g)]);
            vf[df][1] = *reinterpret_cast<const short8*>(&Vsb[kvaddr(r, 4 + g)]);
        }

        // tile B (always active; masks on its own diagonal)
        ATTN_STEP(qb0, qb1, qrowB, laccB, OB, (jt == it2), c0)
        // tile A (active while jt <= it1)
        if (jt <= it1) {
            ATTN_STEP(qa0, qa1, qrowA, laccA, OA, (jt == it1), c0)
        }
    }

    // epilogue: lacc holds the FULL row sum in every lane (ones-MFMA
    // broadcasts the k-reduction to all 16 C-rows).
    {
        const float inv = 1.0f / laccA[0];
#pragma unroll
        for (int df = 0; df < 4; ++df) {
            uint2 st;
            st.x = cvt_pk_bf16(OA[df][0] * inv, OA[df][1] * inv);
            st.y = cvt_pk_bf16(OA[df][2] * inv, OA[df][3] * inv);
            *reinterpret_cast<uint2*>(
                &attb[((size_t)b * SEQ + qrowA) * DMODEL + h * DK + df * 16 + g * 4]) = st;
        }
    }
    {
        const float inv = 1.0f / laccB[0];
#pragma unroll
        for (int df = 0; df < 4; ++df) {
            uint2 st;
            st.x = cvt_pk_bf16(OB[df][0] * inv, OB[df][1] * inv);
            st.y = cvt_pk_bf16(OB[df][2] * inv, OB[df][3] * inv);
            *reinterpret_cast<uint2*>(
                &attb[((size_t)b * SEQ + qrowB) * DMODEL + h * DK + df * 16 + g * 4]) = st;
        }
    }
}

// ---------------------------------------------------------------------------
// Kernel 3: output projection — dbuf counted-vmcnt structure (R2-verified).
// ---------------------------------------------------------------------------
#define OUT_STAGE(bofs, k0s)                                                   \
    _Pragma("unroll")                                                          \
    for (int j = 0; j < 4; ++j)                                                \
        gl_lds16(&attb[(size_t)(m0 + srow[j]) * DMODEL + (k0s) + skc[j]],      \
                 &smem[(bofs) + (tid + 256 * j) * 8]);                         \
    _Pragma("unroll")                                                          \
    for (int j = 4; j < 8; ++j)                                                \
        gl_lds16(&Wob[(size_t)(n0 + srow[j]) * DMODEL + (k0s) + skc[j]],       \
                 &smem[(bofs) + (tid + 256 * j) * 8]);

__global__ __launch_bounds__(256) void out_mfma_kernel(
    const ushort_t* __restrict__ attb,  // [4096,1024] bf16
    const ushort_t* __restrict__ Wob,   // [1024,1024] bf16
    float* __restrict__ out)            // [4096,1024] fp32
{
    __shared__ ushort_t smem[32768];    // 2 x 32KB staging buffers

    const int tid = threadIdx.x;
    const int w = tid >> 6, lane = tid & 63;
    const int lm = lane & 15, g = lane >> 4;
    const int wm = (w >> 1) * 64, wn = (w & 1) * 64;

    // T1: bijective XCD-chunked swizzle (256 = 8 * 32)
    const int lid = blockIdx.y * 8 + blockIdx.x;
    const int swz = (lid & 7) * 32 + (lid >> 3);
    const int m0 = (swz >> 3) * 128, n0 = (swz & 7) * 128;

    int srow[8], skc[8];
#pragma unroll
    for (int j = 0; j < 8; ++j) {
        const int c = tid + 256 * j;
        const int cm = c & 1023;
        const int row = cm >> 3, pp = cm & 7;
        srow[j] = row;
        skc[j] = (pp ^ (row & 7)) * 8;
    }

    v4f acc[4][4] = {};

    OUT_STAGE(0, 0);

    for (int t = 0; t < 16; ++t) {
        const int bofs = (t & 1) << 14;
        if (t < 15) {
            const int nofs = ((t + 1) & 1) << 14;
            OUT_STAGE(nofs, (t + 1) * 64);
            __builtin_amdgcn_sched_barrier(0);
            asm volatile("s_waitcnt vmcnt(8)" ::: "memory");
        } else {
            __builtin_amdgcn_sched_barrier(0);
            asm volatile("s_waitcnt vmcnt(0)" ::: "memory");
        }
        __builtin_amdgcn_s_barrier();
        __builtin_amdgcn_sched_barrier(0);

        __builtin_amdgcn_s_setprio(1);
#pragma unroll
        for (int kb = 0; kb < 2; ++kb) {
            short8 af[4], bfr[4];
#pragma unroll
            for (int mf = 0; mf < 4; ++mf) {
                const int r = wm + mf * 16 + lm;
                af[mf] = *reinterpret_cast<const short8*>(
                    &smem[bofs + (r * 8 + ((kb * 4 + g) ^ (r & 7))) * 8]);
            }
#pragma unroll
            for (int nf = 0; nf < 4; ++nf) {
                const int r = wn + nf * 16 + lm;
                bfr[nf] = *reinterpret_cast<const short8*>(
                    &smem[bofs + 8192 + (r * 8 + ((kb * 4 + g) ^ (r & 7))) * 8]);
            }
#pragma unroll
            for (int mf = 0; mf < 4; ++mf)
#pragma unroll
                for (int nf = 0; nf < 4; ++nf)
                    acc[mf][nf] = __builtin_amdgcn_mfma_f32_16x16x32_bf16(af[mf], bfr[nf], acc[mf][nf], 0, 0, 0);
        }
        __builtin_amdgcn_s_setprio(0);

        __builtin_amdgcn_sched_barrier(0);
        __builtin_amdgcn_s_barrier();
        __builtin_amdgcn_sched_barrier(0);
    }

#pragma unroll
    for (int mf = 0; mf < 4; ++mf)
#pragma unroll
        for (int reg = 0; reg < 4; ++reg) {
            const int m = m0 + wm + mf * 16 + g * 4 + reg;
#pragma unroll
            for (int nf = 0; nf < 4; ++nf) {
                const int n = n0 + wn + nf * 16 + lm;
                out[(size_t)m * DMODEL + n] = acc[mf][nf][reg];
            }
        }
}

// ---------------------------------------------------------------------------
extern "C" void kernel_launch(void* const* d_in, const int* in_sizes, int n_in,
                              void* d_out, int out_size, void* d_ws, size_t ws_size,
                              hipStream_t stream) {
    (void)in_sizes; (void)n_in; (void)out_size; (void)ws_size;

    const float* x    = (const float*)d_in[0];
    const float* Wa   = (const float*)d_in[1];
    const float* Wo   = (const float*)d_in[2];
    const float* rope = (const float*)d_in[3];
    const int*   tp   = (const int*)d_in[4];
    float* out = (float*)d_out;

    char* ws = (char*)d_ws;
    ushort_t* xb   = (ushort_t*)(ws);                       // 8 MB
    ushort_t* Wab  = (ushort_t*)(ws + (8u << 20));          // 6 MB
    ushort_t* Wob  = (ushort_t*)(ws + (14u << 20));         // 2 MB
    float*    cosT = (float*)   (ws + (16u << 20));         // 0.5 MB
    float*    sinT = (float*)   (ws + (16u << 20) + (512u << 10));
    ushort_t* Qb   = (ushort_t*)(ws + (17u << 20));         // 8 MB
    ushort_t* Kb   = (ushort_t*)(ws + (25u << 20));         // 8 MB
    ushort_t* Vtb  = (ushort_t*)(ws + (33u << 20));         // 8 MB
    ushort_t* attb = (ushort_t*)(ws + (41u << 20));         // 8 MB

    dim3 blk(256);
    prep_kernel<<<dim3(8704), blk, 0, stream>>>(x, Wa, Wo, rope, xb, Wab, Wob, cosT, sinT);

    qkv_mfma_kernel<<<dim3(NQKV / 128, M_ROWS / 128), blk, 0, stream>>>(
        xb, Wab, cosT, sinT, tp, Qb, Kb, Vtb);
    attn_mfma_kernel<<<dim3(512), blk, 0, stream>>>(Qb, Kb, Vtb, attb);
    out_mfma_kernel<<<dim3(DMODEL / 128, M_ROWS / 128), blk, 0, stream>>>(attb, Wob, out);
}

// Round 8
// 191.040 us; speedup vs baseline: 1.0309x; 1.0309x over previous
//
#include <hip/hip_runtime.h>
#include <math.h>

// Problem constants
#define B_SZ 2
#define SEQ 2048
#define DMODEL 1024
#define NH 16
#define DK 64
#define NQKV 3072
#define M_ROWS 4096

#define NEG_BIG (-3.0e38f)
#define SCL 0.18033688011112042f   // 0.125 * log2(e)

typedef short short8 __attribute__((ext_vector_type(8)));
typedef float v4f __attribute__((ext_vector_type(4)));
typedef unsigned short ushort_t;

__device__ inline ushort_t f2bf(float f) {
    unsigned u = __float_as_uint(f);
    u += 0x7fffu + ((u >> 16) & 1u);   // RNE
    return (ushort_t)(u >> 16);
}

// packed f32x2 -> bf16x2 (RNE), single VALU op
__device__ __forceinline__ unsigned cvt_pk_bf16(float lo, float hi) {
    unsigned r;
    asm("v_cvt_pk_bf16_f32 %0, %1, %2" : "=v"(r) : "v"(lo), "v"(hi));
    return r;
}
__device__ __forceinline__ void permlane32_swap(unsigned &a, unsigned &b) {
    asm("v_permlane32_swap_b32 %0, %1" : "+v"(a), "+v"(b));
}
__device__ __forceinline__ void permlane16_swap(unsigned &a, unsigned &b) {
    asm("v_permlane16_swap_b32 %0, %1" : "+v"(a), "+v"(b));
}

// async global(16B/lane) -> LDS (wave-uniform base + lane*16)
__device__ __forceinline__ void gl_lds16(const ushort_t* g, ushort_t* l) {
    __builtin_amdgcn_global_load_lds(
        (const __attribute__((address_space(1))) unsigned int*)g,
        (__attribute__((address_space(3))) unsigned int*)l, 16, 0, 0);
}

// attn K/V LDS addressing: [64 rows][64 cols] bf16 (128B rows, UNPADDED),
// 16B-slot XOR swizzle: slot8 ^= (row&7). Conflict-free on both the
// staging-write and fragment-read paths (verified R6: conflicts ~0).
__device__ __forceinline__ int kvaddr(int row, int col8) {
    return row * 64 + ((col8 ^ (row & 7)) << 3);
}

// ---------------------------------------------------------------------------
// Kernel 0: fused prep — fp32->bf16 converts (x, Wa, Wo) + RoPE tables.
// RoPE cos/sin COMPUTED from theta/position (33.5 MB rope tensor never read;
// verified R4-R7: absmax unchanged).
// ---------------------------------------------------------------------------
__global__ __launch_bounds__(256) void prep_kernel(
    const float* __restrict__ x, const float* __restrict__ Wa,
    const float* __restrict__ Wo, const float* __restrict__ rope,
    ushort_t* __restrict__ xb, ushort_t* __restrict__ Wab, ushort_t* __restrict__ Wob,
    float* __restrict__ cosT, float* __restrict__ sinT)
{
    (void)rope;
    const int bid = blockIdx.x;
    if (bid < 8192) {
        const float* src; ushort_t* dst; int i;
        if (bid < 4096)      { src = x;  dst = xb;  i = bid * 256 + threadIdx.x; }
        else if (bid < 7168) { src = Wa; dst = Wab; i = (bid - 4096) * 256 + threadIdx.x; }
        else                 { src = Wo; dst = Wob; i = (bid - 7168) * 256 + threadIdx.x; }
        float4 v = reinterpret_cast<const float4*>(src)[i];
        ushort4 r;
        r.x = f2bf(v.x); r.y = f2bf(v.y); r.z = f2bf(v.z); r.w = f2bf(v.w);
        reinterpret_cast<ushort4*>(dst)[i] = r;
    } else {
        const int i = (bid - 8192) * 256 + threadIdx.x;   // [0, 2048*64)
        const int p = i >> 6, d = i & 63;
        // inv_freq = theta^(-2*(d/2)/64) = exp2(-log2(1e4)/32 * (d>>1))
        const float inv = exp2f(-0.4152410118609203f * (float)(d >> 1));
        const float ang = (float)p * inv;
        float sv, cv;
        sincosf(ang, &sv, &cv);
        cosT[i] = cv;
        sinT[i] = (d & 1) ? sv : -sv;
    }
}

// ---------------------------------------------------------------------------
// Kernel 1: QKV projection + RoPE (R2-verified: 128x128 tile, BK=64,
// XOR-swizzled gl_lds staging, double-buffered, counted vmcnt(8) across raw
// s_barrier, setprio around MFMA, bijective XCD-chunked swizzle).
// Q pre-scaled by SCL = 0.125*log2(e). FROZEN.
// ---------------------------------------------------------------------------
#define ES_STRIDE 136

#define QKV_STAGE(bofs, k0s)                                                   \
    _Pragma("unroll")                                                          \
    for (int j = 0; j < 4; ++j)                                                \
        gl_lds16(&Wab[(size_t)(e0 + srow[j]) * DMODEL + (k0s) + skc[j]],       \
                 &qkv_smem[(bofs) + (tid + 256 * j) * 8]);                     \
    _Pragma("unroll")                                                          \
    for (int j = 4; j < 8; ++j)                                                \
        gl_lds16(&xb[(size_t)(m0 + srow[j]) * DMODEL + (k0s) + skc[j]],        \
                 &qkv_smem[(bofs) + (tid + 256 * j) * 8]);

__global__ __launch_bounds__(256) void qkv_mfma_kernel(
    const ushort_t* __restrict__ xb,   // [4096,1024] bf16
    const ushort_t* __restrict__ Wab,  // [3072,1024] bf16
    const float* __restrict__ cosT, const float* __restrict__ sinT,
    const int* __restrict__ tpos,
    ushort_t* __restrict__ Qb, ushort_t* __restrict__ Kb, ushort_t* __restrict__ Vtb)
{
    __shared__ ushort_t qkv_smem[32768];   // 64 KB: 2 staging buffers
    ushort_t* Es = qkv_smem;               // [128][ES_STRIDE] epilogue alias

    const int tid = threadIdx.x;
    const int w = tid >> 6, lane = tid & 63;
    const int lm = lane & 15, g = lane >> 4;
    const int wm = (w >> 1) * 64, wn = (w & 1) * 64;   // wm: e-dim, wn: m-dim

    // T1: bijective XCD-chunked swizzle (768 = 8 * 96)
    const int lid = blockIdx.y * 24 + blockIdx.x;
    const int swz = (lid & 7) * 96 + (lid >> 3);
    const int e0 = (swz % 24) * 128, m0 = (swz / 24) * 128;

    int srow[8], skc[8];
#pragma unroll
    for (int j = 0; j < 8; ++j) {
        const int c = tid + 256 * j;          // phys chunk 0..2047
        const int cm = c & 1023;
        const int row = cm >> 3, pp = cm & 7;
        srow[j] = row;
        skc[j] = (pp ^ (row & 7)) * 8;        // logical k offset (ushorts)
    }

    v4f acc[4][4] = {};

    QKV_STAGE(0, 0);                          // prologue: tile 0 -> buf0

    for (int t = 0; t < 16; ++t) {
        const int bofs = (t & 1) << 14;       // 0 / 16384 ushorts
        if (t < 15) {
            const int nofs = ((t + 1) & 1) << 14;
            QKV_STAGE(nofs, (t + 1) * 64);    // prefetch next tile (stays in flight)
            __builtin_amdgcn_sched_barrier(0);
            asm volatile("s_waitcnt vmcnt(8)" ::: "memory");   // wait cur's 8 only
        } else {
            __builtin_amdgcn_sched_barrier(0);
            asm volatile("s_waitcnt vmcnt(0)" ::: "memory");
        }
        __builtin_amdgcn_s_barrier();         // cur tile visible to all waves
        __builtin_amdgcn_sched_barrier(0);

        __builtin_amdgcn_s_setprio(1);
#pragma unroll
        for (int kb = 0; kb < 2; ++kb) {
            short8 af[4], bfr[4];
#pragma unroll
            for (int mf = 0; mf < 4; ++mf) {
                const int r = wm + mf * 16 + lm;
                af[mf] = *reinterpret_cast<const short8*>(
                    &qkv_smem[bofs + (r * 8 + ((kb * 4 + g) ^ (r & 7))) * 8]);
            }
#pragma unroll
            for (int nf = 0; nf < 4; ++nf) {
                const int r = wn + nf * 16 + lm;
                bfr[nf] = *reinterpret_cast<const short8*>(
                    &qkv_smem[bofs + 8192 + (r * 8 + ((kb * 4 + g) ^ (r & 7))) * 8]);
            }
#pragma unroll
            for (int mf = 0; mf < 4; ++mf)
#pragma unroll
                for (int nf = 0; nf < 4; ++nf)
                    acc[mf][nf] = __builtin_amdgcn_mfma_f32_16x16x32_bf16(af[mf], bfr[nf], acc[mf][nf], 0, 0, 0);
        }
        __builtin_amdgcn_s_setprio(0);

        __builtin_amdgcn_sched_barrier(0);
        __builtin_amdgcn_s_barrier();         // reads of buf[cur] done before overwrite
        __builtin_amdgcn_sched_barrier(0);
    }

    __syncthreads();   // full fence; Es aliases staging

    const int which = e0 >> 10;            // 0=Q,1=K,2=V (block-uniform)
    const int h0 = (e0 & 1023) >> 6;
    const int bb = m0 >> 11, s0 = m0 & 2047;

    if (which < 2) {
        ushort_t* buf = (which == 0) ? Qb : Kb;
        const float qs = (which == 0) ? SCL : 1.0f;   // fold softmax scale into Q
#pragma unroll
        for (int mf = 0; mf < 4; ++mf) {
            const int ebase = wm + mf * 16 + g * 4;
            const int d0 = (e0 + ebase) & 63;
#pragma unroll
            for (int nf = 0; nf < 4; ++nf) {
                const int sloc = wn + nf * 16 + lm;
                float v[4] = {acc[mf][nf][0], acc[mf][nf][1], acc[mf][nf][2], acc[mf][nf][3]};
                const int p = tpos[s0 + sloc];
                const float4 c4 = *reinterpret_cast<const float4*>(&cosT[p * 64 + d0]);
                const float4 s4 = *reinterpret_cast<const float4*>(&sinT[p * 64 + d0]);
                const float r0 = (c4.x * v[0] + s4.x * v[1]) * qs;
                const float r1 = (c4.y * v[1] + s4.y * v[0]) * qs;
                const float r2 = (c4.z * v[2] + s4.z * v[3]) * qs;
                const float r3 = (c4.w * v[3] + s4.w * v[2]) * qs;
                uint2 pp;
                pp.x = (unsigned)f2bf(r0) | ((unsigned)f2bf(r1) << 16);
                pp.y = (unsigned)f2bf(r2) | ((unsigned)f2bf(r3) << 16);
                *reinterpret_cast<uint2*>(&Es[sloc * ES_STRIDE + ebase]) = pp;
            }
        }
        __syncthreads();
#pragma unroll
        for (int hh = 0; hh < 2; ++hh) {
            ushort_t* dst = buf + (((size_t)bb * NH + h0 + hh) * SEQ + s0) * DK;
#pragma unroll
            for (int t = 0; t < 4; ++t) {
                const int o = (t * 256 + tid) * 8;
                const int sloc = o >> 6, d = o & 63;
                const short8 vv = *reinterpret_cast<const short8*>(&Es[sloc * ES_STRIDE + hh * 64 + d]);
                *reinterpret_cast<short8*>(&dst[o]) = vv;
            }
        }
    } else {
        // V: write Es TRANSPOSED [e_loc][s_loc], store [d][s] slabs to Vtb.
#pragma unroll
        for (int mf = 0; mf < 4; ++mf) {
            const int ebase = wm + mf * 16 + g * 4;
#pragma unroll
            for (int nf = 0; nf < 4; ++nf) {
                const int sloc = wn + nf * 16 + lm;
                Es[(ebase + 0) * ES_STRIDE + sloc] = f2bf(acc[mf][nf][0]);
                Es[(ebase + 1) * ES_STRIDE + sloc] = f2bf(acc[mf][nf][1]);
                Es[(ebase + 2) * ES_STRIDE + sloc] = f2bf(acc[mf][nf][2]);
                Es[(ebase + 3) * ES_STRIDE + sloc] = f2bf(acc[mf][nf][3]);
            }
        }
        __syncthreads();
#pragma unroll
        for (int t = 0; t < 8; ++t) {
            const int c = t * 256 + tid;
            const int hh = c >> 10, cm = c & 1023;
            const int d = cm >> 4, s8c = (cm & 15) * 8;
            const short8 vv = *reinterpret_cast<const short8*>(&Es[(hh * 64 + d) * ES_STRIDE + s8c]);
            ushort_t* dst = Vtb + ((size_t)bb * NH + h0 + hh) * SEQ * DK + (size_t)d * SEQ + s0 + s8c;
            *reinterpret_cast<short8*>(dst) = vv;
        }
    }
}

// ---------------------------------------------------------------------------
// Kernel 2: flash attention — R6-verified merged structure + XOR-swizzled
// conflict-free K/V tiles + VALU-diet softmax. NEW (R8): 2-DEEP register
// prefetch (named even/odd reg sets, loop unrolled x2 — static indexing):
// K/V for tile jt+2 is issued at iter jt and consumed at jt+2, giving ~2
// compute-iterations (~800+ cyc) of load-latency cover vs 1 before.
// Barrier/WAR invariant unchanged (single barrier per iter, dbuf).
// ---------------------------------------------------------------------------
#define ATTN_STEP(QF0, QF1, QROW, LACC, OACC, DIAG, C0)                           \
    {                                                                             \
        v4f sacc[4] = {};                                                         \
        _Pragma("unroll")                                                         \
        for (int nf = 0; nf < 4; ++nf) {                                          \
            sacc[nf] = __builtin_amdgcn_mfma_f32_16x16x32_bf16(kf[nf][0], QF0, sacc[nf], 0, 0, 0); \
            sacc[nf] = __builtin_amdgcn_mfma_f32_16x16x32_bf16(kf[nf][1], QF1, sacc[nf], 0, 0, 0); \
        }                                                                         \
        if (DIAG) {                                                               \
            _Pragma("unroll")                                                     \
            for (int nf = 0; nf < 4; ++nf)                                        \
                _Pragma("unroll")                                                 \
                for (int reg = 0; reg < 4; ++reg) {                               \
                    const int kv = (C0) + nf * 16 + g * 4 + reg;                  \
                    if (kv > (QROW)) sacc[nf][reg] = NEG_BIG;                     \
                }                                                                 \
        }                                                                         \
        unsigned pk0[8];                                                          \
        _Pragma("unroll")                                                         \
        for (int nf = 0; nf < 4; ++nf) {                                          \
            pk0[nf * 2]     = cvt_pk_bf16(exp2f(sacc[nf][0]), exp2f(sacc[nf][1])); \
            pk0[nf * 2 + 1] = cvt_pk_bf16(exp2f(sacc[nf][2]), exp2f(sacc[nf][3])); \
        }                                                                         \
        _Pragma("unroll")                                                         \
        for (int kc = 0; kc < 2; ++kc) {                                          \
            unsigned x0 = pk0[kc * 4 + 0], y0 = pk0[kc * 4 + 2];                  \
            unsigned x1 = pk0[kc * 4 + 1], y1 = pk0[kc * 4 + 3];                  \
            permlane32_swap(x0, y0); permlane16_swap(x0, y0);                     \
            permlane32_swap(x1, y1); permlane16_swap(x1, y1);                     \
            union { unsigned u[4]; short8 s; } pu;                                \
            pu.u[0] = x0; pu.u[1] = x1; pu.u[2] = y0; pu.u[3] = y1;               \
            const short8 pf = pu.s;                                               \
            LACC = __builtin_amdgcn_mfma_f32_16x16x32_bf16(ones8, pf, LACC, 0, 0, 0); \
            _Pragma("unroll")                                                     \
            for (int df = 0; df < 4; ++df)                                        \
                OACC[df] = __builtin_amdgcn_mfma_f32_16x16x32_bf16(vf[df][kc], pf, OACC[df], 0, 0, 0); \
        }                                                                         \
    }

// one full iteration: write regs->LDS, prefetch jt+2 into the SAME reg set,
// barrier, fragment reads, both ATTN_STEPs.
#define ATTN_ITER(JT, KR0, KR1, VR0, VR1)                                         \
    {                                                                             \
        const int c0 = (JT) * 64;                                                 \
        ushort_t* Ksb = Ks[(JT) & 1];                                             \
        ushort_t* Vsb = Vs[(JT) & 1];                                             \
        *reinterpret_cast<short8*>(&Ksb[sw0]) = KR0;                              \
        *reinterpret_cast<short8*>(&Ksb[sw1]) = KR1;                              \
        *reinterpret_cast<short8*>(&Vsb[sw0]) = VR0;                              \
        *reinterpret_cast<short8*>(&Vsb[sw1]) = VR1;                              \
        if ((JT) + 2 <= it2) {                                                    \
            const int c0n = c0 + 128;                                             \
            KR0 = *reinterpret_cast<const short8*>(&Kh[(size_t)(c0n + rr0) * DK + gc0]);  \
            KR1 = *reinterpret_cast<const short8*>(&Kh[(size_t)(c0n + rr1) * DK + gc1]);  \
            VR0 = *reinterpret_cast<const short8*>(&Vth[(size_t)rr0 * SEQ + c0n + gc0]);  \
            VR1 = *reinterpret_cast<const short8*>(&Vth[(size_t)rr1 * SEQ + c0n + gc1]);  \
        }                                                                         \
        __syncthreads();                                                          \
        short8 kf[4][2], vf[4][2];                                                \
        _Pragma("unroll")                                                         \
        for (int nf = 0; nf < 4; ++nf) {                                          \
            const int r = nf * 16 + lm;                                           \
            kf[nf][0] = *reinterpret_cast<const short8*>(&Ksb[kvaddr(r, g)]);     \
            kf[nf][1] = *reinterpret_cast<const short8*>(&Ksb[kvaddr(r, 4 + g)]); \
        }                                                                         \
        _Pragma("unroll")                                                         \
        for (int df = 0; df < 4; ++df) {                                          \
            const int r = df * 16 + lm;                                           \
            vf[df][0] = *reinterpret_cast<const short8*>(&Vsb[kvaddr(r, g)]);     \
            vf[df][1] = *reinterpret_cast<const short8*>(&Vsb[kvaddr(r, 4 + g)]); \
        }                                                                         \
        ATTN_STEP(qb0, qb1, qrowB, laccB, OB, ((JT) == it2), c0)                  \
        if ((JT) <= it1) {                                                        \
            ATTN_STEP(qa0, qa1, qrowA, laccA, OA, ((JT) == it1), c0)              \
        }                                                                         \
    }

__global__ __launch_bounds__(256, 2) void attn_mfma_kernel(
    const ushort_t* __restrict__ Qb, const ushort_t* __restrict__ Kb,
    const ushort_t* __restrict__ Vtb, ushort_t* __restrict__ attb)
{
    __shared__ ushort_t Ks[2][4096];   // [buf] 64x64 bf16, XOR-swizzled slots
    __shared__ ushort_t Vs[2][4096];   // [buf] 64(d) x 64(kv), same swizzle

    const int tid = threadIdx.x;
    const int w = tid >> 6, lane = tid & 63;
    const int lm = lane & 15, g = lane >> 4, lk8 = g * 8;

    const int u = blockIdx.x;                     // 0..15
    const int h = blockIdx.y, b = blockIdx.z;
    const size_t ho = ((size_t)b * NH + h) * SEQ * DK;
    const ushort_t* Qh = Qb + ho;
    const ushort_t* Kh = Kb + ho;
    const ushort_t* Vth = Vtb + ho;               // [DK][SEQ]

    // staging decode: row = tid>>3, 16B chunk c8 = tid&7 (global col c8*8)
    const int rr0 = tid >> 3, c80 = tid & 7;
    const int rr1 = rr0 + 32, c81 = c80;
    const int sw0 = kvaddr(rr0, c80);             // swizzled LDS ushort offset
    const int sw1 = kvaddr(rr1, c81);
    const int gc0 = c80 * 8, gc1 = c81 * 8;       // global col (ushorts)

    const int it1 = u, it2 = 31 - u;              // it1 <= it2; it2 >= 16
    const int qrowA = it1 * 64 + w * 16 + lm;
    const int qrowB = it2 * 64 + w * 16 + lm;

    const short8 qa0 = *reinterpret_cast<const short8*>(&Qh[(size_t)qrowA * DK + lk8]);
    const short8 qa1 = *reinterpret_cast<const short8*>(&Qh[(size_t)qrowA * DK + 32 + lk8]);
    const short8 qb0 = *reinterpret_cast<const short8*>(&Qh[(size_t)qrowB * DK + lk8]);
    const short8 qb1 = *reinterpret_cast<const short8*>(&Qh[(size_t)qrowB * DK + 32 + lk8]);

    const short8 ones8 = {16256, 16256, 16256, 16256, 16256, 16256, 16256, 16256}; // bf16 1.0

    v4f laccA = {}, laccB = {};
    v4f OA[4] = {}, OB[4] = {};

    // 2-deep preload: tiles 0 (even set) and 1 (odd set). it2 >= 16 so both exist.
    short8 kE0 = *reinterpret_cast<const short8*>(&Kh[(size_t)rr0 * DK + gc0]);
    short8 kE1 = *reinterpret_cast<const short8*>(&Kh[(size_t)rr1 * DK + gc1]);
    short8 vE0 = *reinterpret_cast<const short8*>(&Vth[(size_t)rr0 * SEQ + gc0]);
    short8 vE1 = *reinterpret_cast<const short8*>(&Vth[(size_t)rr1 * SEQ + gc1]);
    short8 kO0 = *reinterpret_cast<const short8*>(&Kh[(size_t)(64 + rr0) * DK + gc0]);
    short8 kO1 = *reinterpret_cast<const short8*>(&Kh[(size_t)(64 + rr1) * DK + gc1]);
    short8 vO0 = *reinterpret_cast<const short8*>(&Vth[(size_t)rr0 * SEQ + 64 + gc0]);
    short8 vO1 = *reinterpret_cast<const short8*>(&Vth[(size_t)rr1 * SEQ + 64 + gc1]);

    for (int jt = 0; jt <= it2; jt += 2) {
        ATTN_ITER(jt, kE0, kE1, vE0, vE1)
        if (jt + 1 <= it2) {
            ATTN_ITER(jt + 1, kO0, kO1, vO0, vO1)
        }
    }

    // epilogue: lacc holds the FULL row sum in every lane (ones-MFMA
    // broadcasts the k-reduction to all 16 C-rows).
    {
        const float inv = 1.0f / laccA[0];
#pragma unroll
        for (int df = 0; df < 4; ++df) {
            uint2 st;
            st.x = cvt_pk_bf16(OA[df][0] * inv, OA[df][1] * inv);
            st.y = cvt_pk_bf16(OA[df][2] * inv, OA[df][3] * inv);
            *reinterpret_cast<uint2*>(
                &attb[((size_t)b * SEQ + qrowA) * DMODEL + h * DK + df * 16 + g * 4]) = st;
        }
    }
    {
        const float inv = 1.0f / laccB[0];
#pragma unroll
        for (int df = 0; df < 4; ++df) {
            uint2 st;
            st.x = cvt_pk_bf16(OB[df][0] * inv, OB[df][1] * inv);
            st.y = cvt_pk_bf16(OB[df][2] * inv, OB[df][3] * inv);
            *reinterpret_cast<uint2*>(
                &attb[((size_t)b * SEQ + qrowB) * DMODEL + h * DK + df * 16 + g * 4]) = st;
        }
    }
}

// ---------------------------------------------------------------------------
// Kernel 3: output projection — counted-vmcnt dbuf schedule (R2-verified),
// RE-TILED 128x64 (R8): grid 256 -> 512 blocks = 2 blocks/CU so per-iter
// barrier+vmcnt stalls overlap with a co-resident block (the old 128x128
// grid was exactly 256 blocks = 1/CU, fully exposed — R3's failure mode).
// LDS: dbuf x (A 128x64 + B 64x64) = 48 KB. 6 chunks/thread -> vmcnt(6).
// ---------------------------------------------------------------------------
#define OUT_STAGE(bofs, k0s)                                                   \
    _Pragma("unroll")                                                          \
    for (int j = 0; j < 4; ++j)                                                \
        gl_lds16(&attb[(size_t)(m0 + srow[j]) * DMODEL + (k0s) + skc[j]],      \
                 &smem[(bofs) + (tid + 256 * j) * 8]);                         \
    _Pragma("unroll")                                                          \
    for (int j = 4; j < 6; ++j)                                                \
        gl_lds16(&Wob[(size_t)(n0 + srow[j]) * DMODEL + (k0s) + skc[j]],       \
                 &smem[(bofs) + (tid + 256 * j) * 8]);

__global__ __launch_bounds__(256) void out_mfma_kernel(
    const ushort_t* __restrict__ attb,  // [4096,1024] bf16
    const ushort_t* __restrict__ Wob,   // [1024,1024] bf16
    float* __restrict__ out)            // [4096,1024] fp32
{
    __shared__ ushort_t smem[24576];    // 2 x 24KB staging buffers

    const int tid = threadIdx.x;
    const int w = tid >> 6, lane = tid & 63;
    const int lm = lane & 15, g = lane >> 4;
    const int wm = (w >> 1) * 64, wn = (w & 1) * 32;

    // T1: bijective XCD-chunked swizzle (512 = 8 * 64)
    const int lid = blockIdx.y * 16 + blockIdx.x;
    const int swz = (lid & 7) * 64 + (lid >> 3);
    const int m0 = (swz >> 4) * 128, n0 = (swz & 15) * 64;

    // staging decode: 6 chunks/thread; j<4 -> A (128 rows), j>=4 -> B (64 rows)
    int srow[6], skc[6];
#pragma unroll
    for (int j = 0; j < 6; ++j) {
        const int c = tid + 256 * j;              // phys chunk 0..1535
        const int cm = (j < 4) ? c : (c - 1024);
        const int row = cm >> 3, pp = cm & 7;
        srow[j] = row;
        skc[j] = (pp ^ (row & 7)) * 8;
    }

    v4f acc[4][2] = {};

    OUT_STAGE(0, 0);

    for (int t = 0; t < 16; ++t) {
        const int bofs = (t & 1) * 12288;
        if (t < 15) {
            const int nofs = ((t + 1) & 1) * 12288;
            OUT_STAGE(nofs, (t + 1) * 64);
            __builtin_amdgcn_sched_barrier(0);
            asm volatile("s_waitcnt vmcnt(6)" ::: "memory");
        } else {
            __builtin_amdgcn_sched_barrier(0);
            asm volatile("s_waitcnt vmcnt(0)" ::: "memory");
        }
        __builtin_amdgcn_s_barrier();
        __builtin_amdgcn_sched_barrier(0);

        __builtin_amdgcn_s_setprio(1);
#pragma unroll
        for (int kb = 0; kb < 2; ++kb) {
            short8 af[4], bfr[2];
#pragma unroll
            for (int mf = 0; mf < 4; ++mf) {
                const int r = wm + mf * 16 + lm;
                af[mf] = *reinterpret_cast<const short8*>(
                    &smem[bofs + (r * 8 + ((kb * 4 + g) ^ (r & 7))) * 8]);
            }
#pragma unroll
            for (int nf = 0; nf < 2; ++nf) {
                const int r = wn + nf * 16 + lm;
                bfr[nf] = *reinterpret_cast<const short8*>(
                    &smem[bofs + 8192 + (r * 8 + ((kb * 4 + g) ^ (r & 7))) * 8]);
            }
#pragma unroll
            for (int mf = 0; mf < 4; ++mf)
#pragma unroll
                for (int nf = 0; nf < 2; ++nf)
                    acc[mf][nf] = __builtin_amdgcn_mfma_f32_16x16x32_bf16(af[mf], bfr[nf], acc[mf][nf], 0, 0, 0);
        }
        __builtin_amdgcn_s_setprio(0);

        __builtin_amdgcn_sched_barrier(0);
        __builtin_amdgcn_s_barrier();
        __builtin_amdgcn_sched_barrier(0);
    }

#pragma unroll
    for (int mf = 0; mf < 4; ++mf)
#pragma unroll
        for (int reg = 0; reg < 4; ++reg) {
            const int m = m0 + wm + mf * 16 + g * 4 + reg;
#pragma unroll
            for (int nf = 0; nf < 2; ++nf) {
                const int n = n0 + wn + nf * 16 + lm;
                out[(size_t)m * DMODEL + n] = acc[mf][nf][reg];
            }
        }
}

// ---------------------------------------------------------------------------
extern "C" void kernel_launch(void* const* d_in, const int* in_sizes, int n_in,
                              void* d_out, int out_size, void* d_ws, size_t ws_size,
                              hipStream_t stream) {
    (void)in_sizes; (void)n_in; (void)out_size; (void)ws_size;

    const float* x    = (const float*)d_in[0];
    const float* Wa   = (const float*)d_in[1];
    const float* Wo   = (const float*)d_in[2];
    const float* rope = (const float*)d_in[3];
    const int*   tp   = (const int*)d_in[4];
    float* out = (float*)d_out;

    char* ws = (char*)d_ws;
    ushort_t* xb   = (ushort_t*)(ws);                       // 8 MB
    ushort_t* Wab  = (ushort_t*)(ws + (8u << 20));          // 6 MB
    ushort_t* Wob  = (ushort_t*)(ws + (14u << 20));         // 2 MB
    float*    cosT = (float*)   (ws + (16u << 20));         // 0.5 MB
    float*    sinT = (float*)   (ws + (16u << 20) + (512u << 10));
    ushort_t* Qb   = (ushort_t*)(ws + (17u << 20));         // 8 MB
    ushort_t* Kb   = (ushort_t*)(ws + (25u << 20));         // 8 MB
    ushort_t* Vtb  = (ushort_t*)(ws + (33u << 20));         // 8 MB
    ushort_t* attb = (ushort_t*)(ws + (41u << 20));         // 8 MB

    dim3 blk(256);
    prep_kernel<<<dim3(8704), blk, 0, stream>>>(x, Wa, Wo, rope, xb, Wab, Wob, cosT, sinT);

    qkv_mfma_kernel<<<dim3(NQKV / 128, M_ROWS / 128), blk, 0, stream>>>(
        xb, Wab, cosT, sinT, tp, Qb, Kb, Vtb);
    attn_mfma_kernel<<<dim3(16, NH, B_SZ), blk, 0, stream>>>(Qb, Kb, Vtb, attb);
    out_mfma_kernel<<<dim3(16, 32), blk, 0, stream>>>(attb, Wob, out);
}